// Round 16
// baseline (80.575 us; speedup 1.0000x reference)
//
#include <hip/hip_runtime.h>
#include <hip/hip_fp16.h>

typedef _Float16 f16x8 __attribute__((ext_vector_type(8)));
typedef _Float16 f16x4 __attribute__((ext_vector_type(4)));
typedef float    f32x4 __attribute__((ext_vector_type(4)));

#define NB   32
#define SEQ  1024
#define EDIM 768
#define HD   64
#define MTOT (NB * SEQ)
#define LOG2E 1.44269504088896340736f

// Barrier that does NOT drain outstanding global loads (vmcnt stays counted).
__device__ __forceinline__ void barrier_lgkm_only() {
    __builtin_amdgcn_sched_barrier(0);
    asm volatile("s_waitcnt lgkmcnt(0)" ::: "memory");
    __builtin_amdgcn_sched_barrier(0);
    __builtin_amdgcn_s_barrier();
    __builtin_amdgcn_sched_barrier(0);
}

// ---------------- kernel 0: pack weights -> Wt fp16 [192][768], Wt[c][e] = W[e][c] ----
__global__ __launch_bounds__(256) void pack_w(const float* __restrict__ Wq,
                                              const float* __restrict__ Wk,
                                              const float* __restrict__ Wv,
                                              _Float16* __restrict__ Wt) {
    int c = blockIdx.x;  // 0..191
    const float* src = (c < 64) ? Wq : (c < 128) ? Wk : Wv;
    int cc = c & 63;
    for (int e = threadIdx.x; e < EDIM; e += 256)
        Wt[(size_t)c * EDIM + e] = (_Float16)src[(size_t)e * HD + cc];
}

// ---------------- kernel 1: QKV projection — R12 skeleton @ 4 blocks/CU -------------
// CLEAN concurrency test: 32-row blocks, BK=32, grid 1024, 4 independent
// barrier-groups per CU (R13's test was confounded by removing the Wt LDS).
// Same col-split waves, same 2-deep reg pipeline, same non-draining barriers.
// Per step per wave: 2 A-frag + 3 B-frag ds_reads, 6 MFMAs (B shared across rgs).
#define LOADX_(DST, KT)                                                                \
    DST = *(const f32x4*)&x[(size_t)(m0 + (tid >> 3)) * EDIM + (KT) * 32 + (tid & 7) * 4];

#define STAGEX_(SRC, B) {                                                              \
    f16x4 h;                                                                           \
    h[0] = (_Float16)SRC[0]; h[1] = (_Float16)SRC[1];                                  \
    h[2] = (_Float16)SRC[2]; h[3] = (_Float16)SRC[3];                                  \
    *(f16x4*)&xs[B][tid >> 3][(tid & 7) * 4] = h; }

#define LOADW_(DST, KT)                                                                \
    _Pragma("unroll")                                                                  \
    for (int i = 0; i < 3; ++i) {                                                      \
        int lin = tid + i * 256;                                                       \
        DST[i] = *(const f16x8*)&Wt[(size_t)(lin >> 2) * EDIM + (KT) * 32 + (lin & 3) * 8]; \
    }

#define STAGEW_(SRC, B)                                                                \
    _Pragma("unroll")                                                                  \
    for (int i = 0; i < 3; ++i) {                                                      \
        int lin = tid + i * 256;                                                       \
        *(f16x8*)&wsh[B][lin >> 2][(lin & 3) * 8] = SRC[i];                            \
    }

#define PROJ_STEP(T, XN, WN, XW, WW)                                                   \
  {                                                                                    \
    if ((T) <= 21) { LOADX_(XN, (T) + 2) LOADW_(WN, (T) + 2) }                         \
    {                                                                                  \
      const int cur = (T) & 1;                                                         \
      f16x8 af0 = *(const f16x8*)&xs[cur][lr][lk];                                     \
      f16x8 af1 = *(const f16x8*)&xs[cur][16 + lr][lk];                                \
      _Pragma("unroll")                                                                \
      for (int c = 0; c < 3; ++c) {                                                    \
        f16x8 b0 = *(const f16x8*)&wsh[cur][(wave * 3 + c) * 16 + lr][lk];             \
        acc[0][c] = __builtin_amdgcn_mfma_f32_16x16x32_f16(af0, b0, acc[0][c], 0, 0, 0); \
        acc[1][c] = __builtin_amdgcn_mfma_f32_16x16x32_f16(af1, b0, acc[1][c], 0, 0, 0); \
      }                                                                                \
    }                                                                                  \
    if ((T) <= 22) {                                                                   \
      STAGEX_(XW, ((T) + 1) & 1)                                                       \
      STAGEW_(WW, ((T) + 1) & 1)                                                       \
      barrier_lgkm_only();                                                             \
    }                                                                                  \
  }

__global__ __launch_bounds__(256, 4) void proj_kernel(const float* __restrict__ x,
                                                      const _Float16* __restrict__ Wt,
                                                      _Float16* __restrict__ q16,
                                                      _Float16* __restrict__ k16,
                                                      _Float16* __restrict__ v16t,
                                                      float* __restrict__ part,
                                                      float* __restrict__ ksum) {
    __shared__ _Float16 xs[2][32][40];       // 5.1 KB
    __shared__ _Float16 wsh[2][192][40];     // 30.7 KB -> 4 blocks/CU fit
    __shared__ float red[4][6];
    __shared__ float kred[2][32];
    const int tid = threadIdx.x, wave = tid >> 6, lane = tid & 63;
    const int lr = lane & 15, lk = (lane >> 4) * 8, lrow = (lane >> 4) * 4;
    const int m0 = blockIdx.x * 32;
    const int bb = m0 >> 10;

    f32x4 acc[2][3] = {};    // [row-group][col-block]; nb = wave*3 + c
    f32x4 xA, xB;
    f16x8 wA[3], wB[3];

    // prologue: tile0 -> regs -> LDS buf0; tile1 -> regs (stays in regs)
    LOADX_(xA, 0)
    LOADW_(wA, 0)
    STAGEX_(xA, 0)
    STAGEW_(wA, 0)
    LOADX_(xB, 1)
    LOADW_(wB, 1)
    barrier_lgkm_only();     // tile-1 loads stay in flight

    PROJ_STEP(0,  xA, wA, xB, wB)  PROJ_STEP(1,  xB, wB, xA, wA)
    PROJ_STEP(2,  xA, wA, xB, wB)  PROJ_STEP(3,  xB, wB, xA, wA)
    PROJ_STEP(4,  xA, wA, xB, wB)  PROJ_STEP(5,  xB, wB, xA, wA)
    PROJ_STEP(6,  xA, wA, xB, wB)  PROJ_STEP(7,  xB, wB, xA, wA)
    PROJ_STEP(8,  xA, wA, xB, wB)  PROJ_STEP(9,  xB, wB, xA, wA)
    PROJ_STEP(10, xA, wA, xB, wB)  PROJ_STEP(11, xB, wB, xA, wA)
    PROJ_STEP(12, xA, wA, xB, wB)  PROJ_STEP(13, xB, wB, xA, wA)
    PROJ_STEP(14, xA, wA, xB, wB)  PROJ_STEP(15, xB, wB, xA, wA)
    PROJ_STEP(16, xA, wA, xB, wB)  PROJ_STEP(17, xB, wB, xA, wA)
    PROJ_STEP(18, xA, wA, xB, wB)  PROJ_STEP(19, xB, wB, xA, wA)
    PROJ_STEP(20, xA, wA, xB, wB)  PROJ_STEP(21, xB, wB, xA, wA)
    PROJ_STEP(22, xA, wA, xB, wB)  PROJ_STEP(23, xB, wB, xA, wA)

    // ---- epilogue ----
    #pragma unroll
    for (int rg = 0; rg < 2; ++rg) {
        const int rbase = m0 + rg * 16 + lrow;
        const int rowin = (m0 & 1023) + rg * 16 + lrow;
        #pragma unroll
        for (int c = 0; c < 3; ++c) {
            const int nb = wave * 3 + c;   // wave-uniform
            if (nb < 8) {
                _Float16* dst = (nb < 4) ? q16 : k16;
                int lc = (nb & 3) * 16 + lr;
                #pragma unroll
                for (int j = 0; j < 4; ++j)
                    dst[(size_t)(rbase + j) * HD + lc] = (_Float16)acc[rg][c][j];
            } else {
                int col = (nb & 3) * 16 + lr;
                f16x4 h;
                #pragma unroll
                for (int j = 0; j < 4; ++j) h[j] = (_Float16)acc[rg][c][j];
                *(f16x4*)&v16t[((size_t)(bb * 64 + col)) * SEQ + rowin] = h;
            }
        }
    }

    if (wave == 1 || wave == 2) {   // per-row K sums (wave1: nb4,5 = c1,2; wave2: nb6,7 = c0,1)
        #pragma unroll
        for (int rg = 0; rg < 2; ++rg) {
            #pragma unroll
            for (int j = 0; j < 4; ++j) {
                float ks = (wave == 1) ? (acc[rg][1][j] + acc[rg][2][j])
                                       : (acc[rg][0][j] + acc[rg][1][j]);
                ks += __shfl_xor(ks, 1); ks += __shfl_xor(ks, 2);
                ks += __shfl_xor(ks, 4); ks += __shfl_xor(ks, 8);
                if (lr == 0) kred[wave - 1][rg * 16 + lrow + j] = ks;
            }
        }
    }

    float sq = 0.f, qq = 0.f, sk = 0.f, qk = 0.f, sv = 0.f, qv = 0.f;
    #pragma unroll
    for (int c = 0; c < 3; ++c) {
        const int nb = wave * 3 + c;
        float s = 0.f, q = 0.f;
        #pragma unroll
        for (int rg = 0; rg < 2; ++rg)
            #pragma unroll
            for (int j = 0; j < 4; ++j) { float v = acc[rg][c][j]; s += v; q += v * v; }
        if (nb < 4)      { sq += s; qq += q; }
        else if (nb < 8) { sk += s; qk += q; }
        else             { sv += s; qv += q; }
    }
    #pragma unroll
    for (int off = 1; off < 64; off <<= 1) {
        sq += __shfl_xor(sq, off); qq += __shfl_xor(qq, off);
        sk += __shfl_xor(sk, off); qk += __shfl_xor(qk, off);
        sv += __shfl_xor(sv, off); qv += __shfl_xor(qv, off);
    }
    if (lane == 0) {
        red[wave][0] = sq; red[wave][1] = qq;
        red[wave][2] = sk; red[wave][3] = qk;
        red[wave][4] = sv; red[wave][5] = qv;
    }
    __syncthreads();
    if (tid < 32) ksum[m0 + tid] = kred[0][tid] + kred[1][tid];
    if (tid < 6)
        part[blockIdx.x * 6 + tid] = red[0][tid] + red[1][tid] + red[2][tid] + red[3][tid];
}

// ---------------- kernel 2: flash attention + inlined per-batch stats ---------------
__global__ __launch_bounds__(256) void attn_kernel(const _Float16* __restrict__ q16,
                                                   const _Float16* __restrict__ k16,
                                                   const _Float16* __restrict__ v16t,
                                                   const float* __restrict__ part,
                                                   const float* __restrict__ ksum,
                                                   float* __restrict__ out) {
    __shared__ _Float16 ksm[64][72];
    __shared__ _Float16 vsm[64][72];     // [d][kv]
    __shared__ _Float16 psm[4][16][72];  // per-wave, no barrier needed
    __shared__ float smstats[8];
    const int d_ = blockIdx.x;
    const int b = (d_ & 7) * 4 + ((d_ >> 3) & 3), qt = d_ >> 5;
    const int tid = threadIdx.x, wave = tid >> 6, lane = tid & 63;
    const int lr = lane & 15, lk = (lane >> 4) * 8, lrow = (lane >> 4) * 4;

    // per-batch LN stats from proj partials (32 proj blocks per batch)
    if (tid < 6) {
        double s = 0.0;
        for (int i = 0; i < 32; ++i) s += (double)part[(b * 32 + i) * 6 + tid];
        smstats[tid] = (float)s;
    }
    __syncthreads();
    if (tid < 3) {
        double mean = (double)smstats[tid * 2] / 65536.0;
        double var  = (double)smstats[tid * 2 + 1] / 65536.0 - mean * mean;
        smstats[tid * 2]     = (float)mean;
        smstats[tid * 2 + 1] = (float)(1.0 / sqrt(var + 1e-5));
    }
    __syncthreads();
    const float sscale = smstats[1] * smstats[3] * 0.125f * LOG2E;
    const float adjscale = sscale * smstats[0];   // * mq
    const float mv = smstats[4], rv = smstats[5];

    const int q0 = qt * 64 + wave * 16;
    const _Float16* Qb = q16 + ((size_t)b * SEQ + q0) * HD;
    const float* ksb = ksum + b * SEQ;

    f16x8 aq0 = *(const f16x8*)&Qb[(size_t)lr * HD + lk];
    f16x8 aq1 = *(const f16x8*)&Qb[(size_t)lr * HD + 32 + lk];

    f32x4 o[4] = {};
    float mrow[4], lsum[4];
    #pragma unroll
    for (int j = 0; j < 4; ++j) { mrow[j] = -1e30f; lsum[j] = 0.f; }

    for (int kv0 = 0; kv0 < SEQ; kv0 += 64) {
        for (int i = 0; i < 2; ++i) {
            int lin = tid + i * 256;
            int r = lin >> 3, c = (lin & 7) * 8;
            *(f16x8*)&ksm[r][c] = *(const f16x8*)&k16[((size_t)b * SEQ + kv0 + r) * HD + c];
        }
        for (int i = 0; i < 2; ++i) {
            int lin = tid + i * 256;
            int dd = lin >> 3, c = (lin & 7) * 8;
            *(f16x8*)&vsm[dd][c] = *(const f16x8*)&v16t[((size_t)b * HD + dd) * SEQ + kv0 + c];
        }
        __syncthreads();

        f32x4 sa[4];
        float adjv[4];
        __builtin_amdgcn_s_setprio(1);     // T5: favor MFMA wave on CU scheduler
        #pragma unroll
        for (int cb = 0; cb < 4; ++cb) {
            sa[cb] = (f32x4){0.f, 0.f, 0.f, 0.f};
            f16x8 bk0 = *(const f16x8*)&ksm[cb * 16 + lr][lk];
            f16x8 bk1 = *(const f16x8*)&ksm[cb * 16 + lr][32 + lk];
            sa[cb] = __builtin_amdgcn_mfma_f32_16x16x32_f16(aq0, bk0, sa[cb], 0, 0, 0);
            sa[cb] = __builtin_amdgcn_mfma_f32_16x16x32_f16(aq1, bk1, sa[cb], 0, 0, 0);
            adjv[cb] = adjscale * ksb[kv0 + cb * 16 + lr];
        }
        __builtin_amdgcn_s_setprio(0);

        #pragma unroll
        for (int j = 0; j < 4; ++j) {
            float sv0 = sa[0][j] * sscale - adjv[0];
            float sv1 = sa[1][j] * sscale - adjv[1];
            float sv2 = sa[2][j] * sscale - adjv[2];
            float sv3 = sa[3][j] * sscale - adjv[3];
            float pm = fmaxf(fmaxf(sv0, sv1), fmaxf(sv2, sv3));
            pm = fmaxf(pm, __shfl_xor(pm, 1));
            pm = fmaxf(pm, __shfl_xor(pm, 2));
            pm = fmaxf(pm, __shfl_xor(pm, 4));
            pm = fmaxf(pm, __shfl_xor(pm, 8));
            float mnew  = fmaxf(mrow[j], pm);
            float alpha = exp2f(mrow[j] - mnew);
            mrow[j] = mnew;
            float p0 = exp2f(sv0 - mnew), p1 = exp2f(sv1 - mnew);
            float p2 = exp2f(sv2 - mnew), p3 = exp2f(sv3 - mnew);
            sa[0][j] = p0; sa[1][j] = p1; sa[2][j] = p2; sa[3][j] = p3;
            float rs = (p0 + p1) + (p2 + p3);
            rs += __shfl_xor(rs, 1); rs += __shfl_xor(rs, 2);
            rs += __shfl_xor(rs, 4); rs += __shfl_xor(rs, 8);
            lsum[j] = lsum[j] * alpha + rs;
            o[0][j] *= alpha; o[1][j] *= alpha; o[2][j] *= alpha; o[3][j] *= alpha;
        }
        #pragma unroll
        for (int cb = 0; cb < 4; ++cb)
            #pragma unroll
            for (int j = 0; j < 4; ++j)
                psm[wave][lrow + j][cb * 16 + lr] = (_Float16)sa[cb][j];

        f16x8 pa0 = *(const f16x8*)&psm[wave][lr][lk];
        f16x8 pa1 = *(const f16x8*)&psm[wave][lr][32 + lk];
        __builtin_amdgcn_s_setprio(1);
        #pragma unroll
        for (int db = 0; db < 4; ++db) {
            f16x8 bv0 = *(const f16x8*)&vsm[db * 16 + lr][lk];
            f16x8 bv1 = *(const f16x8*)&vsm[db * 16 + lr][32 + lk];
            o[db] = __builtin_amdgcn_mfma_f32_16x16x32_f16(pa0, bv0, o[db], 0, 0, 0);
            o[db] = __builtin_amdgcn_mfma_f32_16x16x32_f16(pa1, bv1, o[db], 0, 0, 0);
        }
        __builtin_amdgcn_s_setprio(0);
        __syncthreads();
    }

    #pragma unroll
    for (int j = 0; j < 4; ++j) {
        float inv = 1.f / lsum[j];
        size_t row = (size_t)b * SEQ + q0 + lrow + j;
        #pragma unroll
        for (int db = 0; db < 4; ++db)
            out[row * HD + db * 16 + lr] = rv * (o[db][j] * inv - mv);
    }
}

extern "C" void kernel_launch(void* const* d_in, const int* in_sizes, int n_in,
                              void* d_out, int out_size, void* d_ws, size_t ws_size,
                              hipStream_t stream) {
    const float* x  = (const float*)d_in[0];
    const float* Wq = (const float*)d_in[1];
    const float* Wk = (const float*)d_in[2];
    const float* Wv = (const float*)d_in[3];
    float* out = (float*)d_out;
    char* ws = (char*)d_ws;

    _Float16* Wt   = (_Float16*)ws;                 // 294912 B
    float* ksum    = (float*)(ws + 0x51000);        // 128 KB
    float* part    = (float*)(ws + 0x72000);        // 24 KB
    _Float16* q16  = (_Float16*)(ws + 0x100000);    // 4 MiB each
    _Float16* k16  = (_Float16*)(ws + 0x500000);
    _Float16* v16t = (_Float16*)(ws + 0x900000);

    pack_w<<<192, 256, 0, stream>>>(Wq, Wk, Wv, Wt);
    proj_kernel<<<MTOT / 32, 256, 0, stream>>>(x, Wt, q16, k16, v16t, part, ksum);
    attn_kernel<<<NB * 16, 256, 0, stream>>>(q16, k16, v16t, part, ksum, out);
}

// Round 17
// 70.258 us; speedup vs baseline: 1.1468x; 1.1468x over previous
//
#include <hip/hip_runtime.h>
#include <hip/hip_fp16.h>

typedef _Float16 f16x8 __attribute__((ext_vector_type(8)));
typedef _Float16 f16x4 __attribute__((ext_vector_type(4)));
typedef float    f32x4 __attribute__((ext_vector_type(4)));

#define NB   32
#define SEQ  1024
#define EDIM 768
#define HD   64
#define MTOT (NB * SEQ)
#define LOG2E 1.44269504088896340736f

// Barrier that does NOT drain outstanding global loads (vmcnt stays counted).
__device__ __forceinline__ void barrier_lgkm_only() {
    __builtin_amdgcn_sched_barrier(0);
    asm volatile("s_waitcnt lgkmcnt(0)" ::: "memory");
    __builtin_amdgcn_sched_barrier(0);
    __builtin_amdgcn_s_barrier();
    __builtin_amdgcn_sched_barrier(0);
}

// ---------------- kernel 0: pack weights -> Wt fp16 [192][768], Wt[c][e] = W[e][c] ----
__global__ __launch_bounds__(256) void pack_w(const float* __restrict__ Wq,
                                              const float* __restrict__ Wk,
                                              const float* __restrict__ Wv,
                                              _Float16* __restrict__ Wt) {
    int c = blockIdx.x;  // 0..191
    const float* src = (c < 64) ? Wq : (c < 128) ? Wk : Wv;
    int cc = c & 63;
    for (int e = threadIdx.x; e < EDIM; e += 256)
        Wt[(size_t)c * EDIM + e] = (_Float16)src[(size_t)e * HD + cc];
}

// ---------------- kernel 1: QKV projection (R12 structure — best measured) ----------
#define PROJ_STEP(T, XN, WN, XW, WW)                                                   \
  {                                                                                    \
    if ((T) <= 9) {   /* issue global loads for tile T+2 */                            \
      const int e0 = ((T) + 2) * 64;                                                   \
      _Pragma("unroll")                                                                \
      for (int i = 0; i < 4; ++i) {                                                    \
        int lin = tid + i * 256, r = lin >> 4, c4 = (lin & 15) * 4;                    \
        XN[i] = *(const f32x4*)&x[(size_t)(m0 + r) * EDIM + e0 + c4];                  \
      }                                                                                \
      _Pragma("unroll")                                                                \
      for (int i = 0; i < 6; ++i) {                                                    \
        int lin = tid + i * 256, c = lin >> 3, c8 = (lin & 7) * 8;                     \
        WN[i] = *(const f16x8*)&Wt[(size_t)c * EDIM + e0 + c8];                        \
      }                                                                                \
    }                                                                                  \
    {   /* MFMA on current buffer */                                                   \
      const int cur = (T) & 1;                                                         \
      f16x8 af[4][2];                                                                  \
      _Pragma("unroll")                                                                \
      for (int rg = 0; rg < 4; ++rg) {                                                 \
        af[rg][0] = *(const f16x8*)&xs[cur][rg * 16 + lr][lk];                         \
        af[rg][1] = *(const f16x8*)&xs[cur][rg * 16 + lr][32 + lk];                    \
      }                                                                                \
      _Pragma("unroll")                                                                \
      for (int c = 0; c < 3; ++c) {                                                    \
        const int nb = wave * 3 + c;                                                   \
        f16x8 b0 = *(const f16x8*)&wsh[cur][nb * 16 + lr][lk];                         \
        f16x8 b1 = *(const f16x8*)&wsh[cur][nb * 16 + lr][32 + lk];                    \
        _Pragma("unroll")                                                              \
        for (int rg = 0; rg < 4; ++rg) {                                               \
          acc[rg][c] = __builtin_amdgcn_mfma_f32_16x16x32_f16(af[rg][0], b0, acc[rg][c], 0, 0, 0); \
          acc[rg][c] = __builtin_amdgcn_mfma_f32_16x16x32_f16(af[rg][1], b1, acc[rg][c], 0, 0, 0); \
        }                                                                              \
      }                                                                                \
    }                                                                                  \
    if ((T) <= 10) {  /* ds_write tile T+1 (regs loaded one iter ago) + raw barrier */ \
      const int nxt = ((T) + 1) & 1;                                                   \
      _Pragma("unroll")                                                                \
      for (int i = 0; i < 4; ++i) {                                                    \
        int lin = tid + i * 256, r = lin >> 4, c4 = (lin & 15) * 4;                    \
        f16x4 h;                                                                       \
        h[0] = (_Float16)XW[i][0]; h[1] = (_Float16)XW[i][1];                          \
        h[2] = (_Float16)XW[i][2]; h[3] = (_Float16)XW[i][3];                          \
        *(f16x4*)&xs[nxt][r][c4] = h;                                                  \
      }                                                                                \
      _Pragma("unroll")                                                                \
      for (int i = 0; i < 6; ++i) {                                                    \
        int lin = tid + i * 256, c = lin >> 3, c8 = (lin & 7) * 8;                     \
        *(f16x8*)&wsh[nxt][c][c8] = WW[i];                                             \
      }                                                                                \
      barrier_lgkm_only();                                                             \
    }                                                                                  \
  }

__global__ __launch_bounds__(256, 2) void proj_kernel(const float* __restrict__ x,
                                                      const _Float16* __restrict__ Wt,
                                                      _Float16* __restrict__ q16,
                                                      _Float16* __restrict__ k16,
                                                      _Float16* __restrict__ v16t,
                                                      float* __restrict__ part,
                                                      float* __restrict__ ksum) {
    __shared__ _Float16 xs[2][64][72];
    __shared__ _Float16 wsh[2][192][72];
    __shared__ float red[4][6];
    __shared__ float kred[2][64];
    const int tid = threadIdx.x, wave = tid >> 6, lane = tid & 63;
    const int lr = lane & 15, lk = (lane >> 4) * 8, lrow = (lane >> 4) * 4;
    const int m0 = blockIdx.x * 64;
    const int bb = m0 >> 10;

    f32x4 acc[4][3] = {};    // [row-group][col-block]; nb = wave*3 + c
    f32x4 xv0[4], xv1[4];
    f16x8 wv0[6], wv1[6];

    // prologue: tile0 -> regs -> LDS buf0; tile1 -> regs (stays in regs)
    #pragma unroll
    for (int i = 0; i < 4; ++i) {
        int lin = tid + i * 256, r = lin >> 4, c4 = (lin & 15) * 4;
        xv0[i] = *(const f32x4*)&x[(size_t)(m0 + r) * EDIM + c4];
    }
    #pragma unroll
    for (int i = 0; i < 6; ++i) {
        int lin = tid + i * 256, c = lin >> 3, c8 = (lin & 7) * 8;
        wv0[i] = *(const f16x8*)&Wt[(size_t)c * EDIM + c8];
    }
    #pragma unroll
    for (int i = 0; i < 4; ++i) {
        int lin = tid + i * 256, r = lin >> 4, c4 = (lin & 15) * 4;
        f16x4 h;
        h[0] = (_Float16)xv0[i][0]; h[1] = (_Float16)xv0[i][1];
        h[2] = (_Float16)xv0[i][2]; h[3] = (_Float16)xv0[i][3];
        *(f16x4*)&xs[0][r][c4] = h;
    }
    #pragma unroll
    for (int i = 0; i < 6; ++i) {
        int lin = tid + i * 256, c = lin >> 3, c8 = (lin & 7) * 8;
        *(f16x8*)&wsh[0][c][c8] = wv0[i];
    }
    #pragma unroll
    for (int i = 0; i < 4; ++i) {
        int lin = tid + i * 256, r = lin >> 4, c4 = (lin & 15) * 4;
        xv1[i] = *(const f32x4*)&x[(size_t)(m0 + r) * EDIM + 64 + c4];
    }
    #pragma unroll
    for (int i = 0; i < 6; ++i) {
        int lin = tid + i * 256, c = lin >> 3, c8 = (lin & 7) * 8;
        wv1[i] = *(const f16x8*)&Wt[(size_t)c * EDIM + 64 + c8];
    }
    barrier_lgkm_only();    // tile-1 loads stay in flight

    PROJ_STEP(0,  xv0, wv0, xv1, wv1)
    PROJ_STEP(1,  xv1, wv1, xv0, wv0)
    PROJ_STEP(2,  xv0, wv0, xv1, wv1)
    PROJ_STEP(3,  xv1, wv1, xv0, wv0)
    PROJ_STEP(4,  xv0, wv0, xv1, wv1)
    PROJ_STEP(5,  xv1, wv1, xv0, wv0)
    PROJ_STEP(6,  xv0, wv0, xv1, wv1)
    PROJ_STEP(7,  xv1, wv1, xv0, wv0)
    PROJ_STEP(8,  xv0, wv0, xv1, wv1)
    PROJ_STEP(9,  xv1, wv1, xv0, wv0)
    PROJ_STEP(10, xv0, wv0, xv1, wv1)
    PROJ_STEP(11, xv1, wv1, xv0, wv0)

    // ---- epilogue ----
    #pragma unroll
    for (int rg = 0; rg < 4; ++rg) {
        const int rbase = m0 + rg * 16 + lrow;
        const int rowin = (m0 & 1023) + rg * 16 + lrow;
        #pragma unroll
        for (int c = 0; c < 3; ++c) {
            const int nb = wave * 3 + c;   // wave-uniform
            if (nb < 8) {
                _Float16* dst = (nb < 4) ? q16 : k16;
                int lc = (nb & 3) * 16 + lr;
                #pragma unroll
                for (int j = 0; j < 4; ++j)
                    dst[(size_t)(rbase + j) * HD + lc] = (_Float16)acc[rg][c][j];
            } else {
                int col = (nb & 3) * 16 + lr;
                f16x4 h;
                #pragma unroll
                for (int j = 0; j < 4; ++j) h[j] = (_Float16)acc[rg][c][j];
                *(f16x4*)&v16t[((size_t)(bb * 64 + col)) * SEQ + rowin] = h;
            }
        }
    }

    if (wave == 1 || wave == 2) {   // per-row K sums (wave1: nb4,5 = c1,2; wave2: nb6,7 = c0,1)
        #pragma unroll
        for (int rg = 0; rg < 4; ++rg) {
            #pragma unroll
            for (int j = 0; j < 4; ++j) {
                float ks = (wave == 1) ? (acc[rg][1][j] + acc[rg][2][j])
                                       : (acc[rg][0][j] + acc[rg][1][j]);
                ks += __shfl_xor(ks, 1); ks += __shfl_xor(ks, 2);
                ks += __shfl_xor(ks, 4); ks += __shfl_xor(ks, 8);
                if (lr == 0) kred[wave - 1][rg * 16 + lrow + j] = ks;
            }
        }
    }

    float sq = 0.f, qq = 0.f, sk = 0.f, qk = 0.f, sv = 0.f, qv = 0.f;
    #pragma unroll
    for (int c = 0; c < 3; ++c) {
        const int nb = wave * 3 + c;
        float s = 0.f, q = 0.f;
        #pragma unroll
        for (int rg = 0; rg < 4; ++rg)
            #pragma unroll
            for (int j = 0; j < 4; ++j) { float v = acc[rg][c][j]; s += v; q += v * v; }
        if (nb < 4)      { sq += s; qq += q; }
        else if (nb < 8) { sk += s; qk += q; }
        else             { sv += s; qv += q; }
    }
    #pragma unroll
    for (int off = 1; off < 64; off <<= 1) {
        sq += __shfl_xor(sq, off); qq += __shfl_xor(qq, off);
        sk += __shfl_xor(sk, off); qk += __shfl_xor(qk, off);
        sv += __shfl_xor(sv, off); qv += __shfl_xor(qv, off);
    }
    if (lane == 0) {
        red[wave][0] = sq; red[wave][1] = qq;
        red[wave][2] = sk; red[wave][3] = qk;
        red[wave][4] = sv; red[wave][5] = qv;
    }
    __syncthreads();
    if (tid < 64) ksum[m0 + tid] = kred[0][tid] + kred[1][tid];
    if (tid < 6)
        part[blockIdx.x * 6 + tid] = red[0][tid] + red[1][tid] + red[2][tid] + red[3][tid];
}

// ---------------- kernel 2: flash attention + inlined per-batch stats ---------------
__global__ __launch_bounds__(256) void attn_kernel(const _Float16* __restrict__ q16,
                                                   const _Float16* __restrict__ k16,
                                                   const _Float16* __restrict__ v16t,
                                                   const float* __restrict__ part,
                                                   const float* __restrict__ ksum,
                                                   float* __restrict__ out) {
    __shared__ _Float16 ksm[64][72];
    __shared__ _Float16 vsm[64][72];     // [d][kv]
    __shared__ _Float16 psm[4][16][72];  // per-wave, no barrier needed
    __shared__ float smstats[8];
    const int d_ = blockIdx.x;
    const int b = (d_ & 7) * 4 + ((d_ >> 3) & 3), qt = d_ >> 5;
    const int tid = threadIdx.x, wave = tid >> 6, lane = tid & 63;
    const int lr = lane & 15, lk = (lane >> 4) * 8, lrow = (lane >> 4) * 4;

    // per-batch LN stats from proj partials (replaces stats_reduce kernel)
    if (tid < 6) {
        double s = 0.0;
        for (int i = 0; i < 16; ++i) s += (double)part[(b * 16 + i) * 6 + tid];
        smstats[tid] = (float)s;
    }
    __syncthreads();
    if (tid < 3) {
        double mean = (double)smstats[tid * 2] / 65536.0;
        double var  = (double)smstats[tid * 2 + 1] / 65536.0 - mean * mean;
        smstats[tid * 2]     = (float)mean;
        smstats[tid * 2 + 1] = (float)(1.0 / sqrt(var + 1e-5));
    }
    __syncthreads();
    const float sscale = smstats[1] * smstats[3] * 0.125f * LOG2E;
    const float adjscale = sscale * smstats[0];   // * mq
    const float mv = smstats[4], rv = smstats[5];

    const int q0 = qt * 64 + wave * 16;
    const _Float16* Qb = q16 + ((size_t)b * SEQ + q0) * HD;
    const float* ksb = ksum + b * SEQ;

    f16x8 aq0 = *(const f16x8*)&Qb[(size_t)lr * HD + lk];
    f16x8 aq1 = *(const f16x8*)&Qb[(size_t)lr * HD + 32 + lk];

    f32x4 o[4] = {};
    float mrow[4], lsum[4];
    #pragma unroll
    for (int j = 0; j < 4; ++j) { mrow[j] = -1e30f; lsum[j] = 0.f; }

    for (int kv0 = 0; kv0 < SEQ; kv0 += 64) {
        for (int i = 0; i < 2; ++i) {
            int lin = tid + i * 256;
            int r = lin >> 3, c = (lin & 7) * 8;
            *(f16x8*)&ksm[r][c] = *(const f16x8*)&k16[((size_t)b * SEQ + kv0 + r) * HD + c];
        }
        for (int i = 0; i < 2; ++i) {
            int lin = tid + i * 256;
            int dd = lin >> 3, c = (lin & 7) * 8;
            *(f16x8*)&vsm[dd][c] = *(const f16x8*)&v16t[((size_t)b * HD + dd) * SEQ + kv0 + c];
        }
        __syncthreads();

        f32x4 sa[4];
        float adjv[4];
        __builtin_amdgcn_s_setprio(1);     // T5: favor MFMA wave on CU scheduler
        #pragma unroll
        for (int cb = 0; cb < 4; ++cb) {
            sa[cb] = (f32x4){0.f, 0.f, 0.f, 0.f};
            f16x8 bk0 = *(const f16x8*)&ksm[cb * 16 + lr][lk];
            f16x8 bk1 = *(const f16x8*)&ksm[cb * 16 + lr][32 + lk];
            sa[cb] = __builtin_amdgcn_mfma_f32_16x16x32_f16(aq0, bk0, sa[cb], 0, 0, 0);
            sa[cb] = __builtin_amdgcn_mfma_f32_16x16x32_f16(aq1, bk1, sa[cb], 0, 0, 0);
            adjv[cb] = adjscale * ksb[kv0 + cb * 16 + lr];
        }
        __builtin_amdgcn_s_setprio(0);

        #pragma unroll
        for (int j = 0; j < 4; ++j) {
            float sv0 = sa[0][j] * sscale - adjv[0];
            float sv1 = sa[1][j] * sscale - adjv[1];
            float sv2 = sa[2][j] * sscale - adjv[2];
            float sv3 = sa[3][j] * sscale - adjv[3];
            float pm = fmaxf(fmaxf(sv0, sv1), fmaxf(sv2, sv3));
            pm = fmaxf(pm, __shfl_xor(pm, 1));
            pm = fmaxf(pm, __shfl_xor(pm, 2));
            pm = fmaxf(pm, __shfl_xor(pm, 4));
            pm = fmaxf(pm, __shfl_xor(pm, 8));
            float mnew  = fmaxf(mrow[j], pm);
            float alpha = exp2f(mrow[j] - mnew);
            mrow[j] = mnew;
            float p0 = exp2f(sv0 - mnew), p1 = exp2f(sv1 - mnew);
            float p2 = exp2f(sv2 - mnew), p3 = exp2f(sv3 - mnew);
            sa[0][j] = p0; sa[1][j] = p1; sa[2][j] = p2; sa[3][j] = p3;
            float rs = (p0 + p1) + (p2 + p3);
            rs += __shfl_xor(rs, 1); rs += __shfl_xor(rs, 2);
            rs += __shfl_xor(rs, 4); rs += __shfl_xor(rs, 8);
            lsum[j] = lsum[j] * alpha + rs;
            o[0][j] *= alpha; o[1][j] *= alpha; o[2][j] *= alpha; o[3][j] *= alpha;
        }
        #pragma unroll
        for (int cb = 0; cb < 4; ++cb)
            #pragma unroll
            for (int j = 0; j < 4; ++j)
                psm[wave][lrow + j][cb * 16 + lr] = (_Float16)sa[cb][j];

        f16x8 pa0 = *(const f16x8*)&psm[wave][lr][lk];
        f16x8 pa1 = *(const f16x8*)&psm[wave][lr][32 + lk];
        __builtin_amdgcn_s_setprio(1);
        #pragma unroll
        for (int db = 0; db < 4; ++db) {
            f16x8 bv0 = *(const f16x8*)&vsm[db * 16 + lr][lk];
            f16x8 bv1 = *(const f16x8*)&vsm[db * 16 + lr][32 + lk];
            o[db] = __builtin_amdgcn_mfma_f32_16x16x32_f16(pa0, bv0, o[db], 0, 0, 0);
            o[db] = __builtin_amdgcn_mfma_f32_16x16x32_f16(pa1, bv1, o[db], 0, 0, 0);
        }
        __builtin_amdgcn_s_setprio(0);
        __syncthreads();
    }

    #pragma unroll
    for (int j = 0; j < 4; ++j) {
        float inv = 1.f / lsum[j];
        size_t row = (size_t)b * SEQ + q0 + lrow + j;
        #pragma unroll
        for (int db = 0; db < 4; ++db)
            out[row * HD + db * 16 + lr] = rv * (o[db][j] * inv - mv);
    }
}

extern "C" void kernel_launch(void* const* d_in, const int* in_sizes, int n_in,
                              void* d_out, int out_size, void* d_ws, size_t ws_size,
                              hipStream_t stream) {
    const float* x  = (const float*)d_in[0];
    const float* Wq = (const float*)d_in[1];
    const float* Wk = (const float*)d_in[2];
    const float* Wv = (const float*)d_in[3];
    float* out = (float*)d_out;
    char* ws = (char*)d_ws;

    _Float16* Wt   = (_Float16*)ws;                 // 294912 B
    float* ksum    = (float*)(ws + 0x51000);        // 128 KB
    float* part    = (float*)(ws + 0x72000);        // 12 KB
    _Float16* q16  = (_Float16*)(ws + 0x100000);    // 4 MiB each
    _Float16* k16  = (_Float16*)(ws + 0x500000);
    _Float16* v16t = (_Float16*)(ws + 0x900000);

    pack_w<<<192, 256, 0, stream>>>(Wq, Wk, Wv, Wt);
    proj_kernel<<<MTOT / 64, 256, 0, stream>>>(x, Wt, q16, k16, v16t, part, ksum);
    attn_kernel<<<NB * 16, 256, 0, stream>>>(q16, k16, v16t, part, ksum, out);
}

// Round 18
// 70.231 us; speedup vs baseline: 1.1473x; 1.0004x over previous
//
#include <hip/hip_runtime.h>
#include <hip/hip_fp16.h>

typedef _Float16 f16x8 __attribute__((ext_vector_type(8)));
typedef _Float16 f16x4 __attribute__((ext_vector_type(4)));
typedef float    f32x4 __attribute__((ext_vector_type(4)));

#define NB   32
#define SEQ  1024
#define EDIM 768
#define HD   64
#define MTOT (NB * SEQ)
#define LOG2E 1.44269504088896340736f

// Barrier that does NOT drain outstanding global loads (vmcnt stays counted).
__device__ __forceinline__ void barrier_lgkm_only() {
    __builtin_amdgcn_sched_barrier(0);
    asm volatile("s_waitcnt lgkmcnt(0)" ::: "memory");
    __builtin_amdgcn_sched_barrier(0);
    __builtin_amdgcn_s_barrier();
    __builtin_amdgcn_sched_barrier(0);
}

// ---------------- kernel 0: pack weights -> Wt fp16 [192][768], Wt[c][e] = W[e][c] ----
__global__ __launch_bounds__(256) void pack_w(const float* __restrict__ Wq,
                                              const float* __restrict__ Wk,
                                              const float* __restrict__ Wv,
                                              _Float16* __restrict__ Wt) {
    int c = blockIdx.x;  // 0..191
    const float* src = (c < 64) ? Wq : (c < 128) ? Wk : Wv;
    int cc = c & 63;
    for (int e = threadIdx.x; e < EDIM; e += 256)
        Wt[(size_t)c * EDIM + e] = (_Float16)src[(size_t)e * HD + cc];
}

// ---------------- kernel 1: QKV projection (R12 structure + phase-shifted K order) ---
// Odd-phase blocks rotate the K-tile order by 6 (accumulation is commutative), so
// co-resident blocks on a CU issue load bursts / hit barriers OUT of phase — one
// block's MFMA window covers the other's delivery burst.
#define KIDX(N) ((((N) + koff) >= 12) ? ((N) + koff - 12) : ((N) + koff))

#define PROJ_STEP(T, XN, WN, XW, WW)                                                   \
  {                                                                                    \
    if ((T) <= 9) {   /* issue global loads for (rotated) tile T+2 */                  \
      const int e0 = KIDX((T) + 2) * 64;                                               \
      _Pragma("unroll")                                                                \
      for (int i = 0; i < 4; ++i) {                                                    \
        int lin = tid + i * 256, r = lin >> 4, c4 = (lin & 15) * 4;                    \
        XN[i] = *(const f32x4*)&x[(size_t)(m0 + r) * EDIM + e0 + c4];                  \
      }                                                                                \
      _Pragma("unroll")                                                                \
      for (int i = 0; i < 6; ++i) {                                                    \
        int lin = tid + i * 256, c = lin >> 3, c8 = (lin & 7) * 8;                     \
        WN[i] = *(const f16x8*)&Wt[(size_t)c * EDIM + e0 + c8];                        \
      }                                                                                \
    }                                                                                  \
    {   /* MFMA on current buffer */                                                   \
      const int cur = (T) & 1;                                                         \
      f16x8 af[4][2];                                                                  \
      _Pragma("unroll")                                                                \
      for (int rg = 0; rg < 4; ++rg) {                                                 \
        af[rg][0] = *(const f16x8*)&xs[cur][rg * 16 + lr][lk];                         \
        af[rg][1] = *(const f16x8*)&xs[cur][rg * 16 + lr][32 + lk];                    \
      }                                                                                \
      _Pragma("unroll")                                                                \
      for (int c = 0; c < 3; ++c) {                                                    \
        const int nb = wave * 3 + c;                                                   \
        f16x8 b0 = *(const f16x8*)&wsh[cur][nb * 16 + lr][lk];                         \
        f16x8 b1 = *(const f16x8*)&wsh[cur][nb * 16 + lr][32 + lk];                    \
        _Pragma("unroll")                                                              \
        for (int rg = 0; rg < 4; ++rg) {                                               \
          acc[rg][c] = __builtin_amdgcn_mfma_f32_16x16x32_f16(af[rg][0], b0, acc[rg][c], 0, 0, 0); \
          acc[rg][c] = __builtin_amdgcn_mfma_f32_16x16x32_f16(af[rg][1], b1, acc[rg][c], 0, 0, 0); \
        }                                                                              \
      }                                                                                \
    }                                                                                  \
    if ((T) <= 10) {  /* ds_write tile T+1 (regs loaded one iter ago) + raw barrier */ \
      const int nxt = ((T) + 1) & 1;                                                   \
      _Pragma("unroll")                                                                \
      for (int i = 0; i < 4; ++i) {                                                    \
        int lin = tid + i * 256, r = lin >> 4, c4 = (lin & 15) * 4;                    \
        f16x4 h;                                                                       \
        h[0] = (_Float16)XW[i][0]; h[1] = (_Float16)XW[i][1];                          \
        h[2] = (_Float16)XW[i][2]; h[3] = (_Float16)XW[i][3];                          \
        *(f16x4*)&xs[nxt][r][c4] = h;                                                  \
      }                                                                                \
      _Pragma("unroll")                                                                \
      for (int i = 0; i < 6; ++i) {                                                    \
        int lin = tid + i * 256, c = lin >> 3, c8 = (lin & 7) * 8;                     \
        *(f16x8*)&wsh[nxt][c][c8] = WW[i];                                             \
      }                                                                                \
      barrier_lgkm_only();                                                             \
    }                                                                                  \
  }

__global__ __launch_bounds__(256, 2) void proj_kernel(const float* __restrict__ x,
                                                      const _Float16* __restrict__ Wt,
                                                      _Float16* __restrict__ q16,
                                                      _Float16* __restrict__ k16,
                                                      _Float16* __restrict__ v16t,
                                                      float* __restrict__ part,
                                                      float* __restrict__ ksum) {
    __shared__ _Float16 xs[2][64][72];
    __shared__ _Float16 wsh[2][192][72];
    __shared__ float red[4][6];
    __shared__ float kred[2][64];
    const int tid = threadIdx.x, wave = tid >> 6, lane = tid & 63;
    const int lr = lane & 15, lk = (lane >> 4) * 8, lrow = (lane >> 4) * 4;
    const int m0 = blockIdx.x * 64;
    const int bb = m0 >> 10;
    // phase shift: decorrelate co-resident blocks under either (i,i+1) or (i,i+256) pairing
    const int koff = ((blockIdx.x ^ (blockIdx.x >> 8)) & 1) * 6;

    f32x4 acc[4][3] = {};    // [row-group][col-block]; nb = wave*3 + c
    f32x4 xv0[4], xv1[4];
    f16x8 wv0[6], wv1[6];

    // prologue: tile KIDX(0) -> regs -> LDS buf0; tile KIDX(1) -> regs
    const int e00 = KIDX(0) * 64, e01 = KIDX(1) * 64;
    #pragma unroll
    for (int i = 0; i < 4; ++i) {
        int lin = tid + i * 256, r = lin >> 4, c4 = (lin & 15) * 4;
        xv0[i] = *(const f32x4*)&x[(size_t)(m0 + r) * EDIM + e00 + c4];
    }
    #pragma unroll
    for (int i = 0; i < 6; ++i) {
        int lin = tid + i * 256, c = lin >> 3, c8 = (lin & 7) * 8;
        wv0[i] = *(const f16x8*)&Wt[(size_t)c * EDIM + e00 + c8];
    }
    #pragma unroll
    for (int i = 0; i < 4; ++i) {
        int lin = tid + i * 256, r = lin >> 4, c4 = (lin & 15) * 4;
        f16x4 h;
        h[0] = (_Float16)xv0[i][0]; h[1] = (_Float16)xv0[i][1];
        h[2] = (_Float16)xv0[i][2]; h[3] = (_Float16)xv0[i][3];
        *(f16x4*)&xs[0][r][c4] = h;
    }
    #pragma unroll
    for (int i = 0; i < 6; ++i) {
        int lin = tid + i * 256, c = lin >> 3, c8 = (lin & 7) * 8;
        *(f16x8*)&wsh[0][c][c8] = wv0[i];
    }
    #pragma unroll
    for (int i = 0; i < 4; ++i) {
        int lin = tid + i * 256, r = lin >> 4, c4 = (lin & 15) * 4;
        xv1[i] = *(const f32x4*)&x[(size_t)(m0 + r) * EDIM + e01 + c4];
    }
    #pragma unroll
    for (int i = 0; i < 6; ++i) {
        int lin = tid + i * 256, c = lin >> 3, c8 = (lin & 7) * 8;
        wv1[i] = *(const f16x8*)&Wt[(size_t)c * EDIM + e01 + c8];
    }
    barrier_lgkm_only();    // tile-1 loads stay in flight

    PROJ_STEP(0,  xv0, wv0, xv1, wv1)
    PROJ_STEP(1,  xv1, wv1, xv0, wv0)
    PROJ_STEP(2,  xv0, wv0, xv1, wv1)
    PROJ_STEP(3,  xv1, wv1, xv0, wv0)
    PROJ_STEP(4,  xv0, wv0, xv1, wv1)
    PROJ_STEP(5,  xv1, wv1, xv0, wv0)
    PROJ_STEP(6,  xv0, wv0, xv1, wv1)
    PROJ_STEP(7,  xv1, wv1, xv0, wv0)
    PROJ_STEP(8,  xv0, wv0, xv1, wv1)
    PROJ_STEP(9,  xv1, wv1, xv0, wv0)
    PROJ_STEP(10, xv0, wv0, xv1, wv1)
    PROJ_STEP(11, xv1, wv1, xv0, wv0)

    // ---- epilogue ----
    #pragma unroll
    for (int rg = 0; rg < 4; ++rg) {
        const int rbase = m0 + rg * 16 + lrow;
        const int rowin = (m0 & 1023) + rg * 16 + lrow;
        #pragma unroll
        for (int c = 0; c < 3; ++c) {
            const int nb = wave * 3 + c;   // wave-uniform
            if (nb < 8) {
                _Float16* dst = (nb < 4) ? q16 : k16;
                int lc = (nb & 3) * 16 + lr;
                #pragma unroll
                for (int j = 0; j < 4; ++j)
                    dst[(size_t)(rbase + j) * HD + lc] = (_Float16)acc[rg][c][j];
            } else {
                int col = (nb & 3) * 16 + lr;
                f16x4 h;
                #pragma unroll
                for (int j = 0; j < 4; ++j) h[j] = (_Float16)acc[rg][c][j];
                *(f16x4*)&v16t[((size_t)(bb * 64 + col)) * SEQ + rowin] = h;
            }
        }
    }

    if (wave == 1 || wave == 2) {   // per-row K sums (wave1: nb4,5 = c1,2; wave2: nb6,7 = c0,1)
        #pragma unroll
        for (int rg = 0; rg < 4; ++rg) {
            #pragma unroll
            for (int j = 0; j < 4; ++j) {
                float ks = (wave == 1) ? (acc[rg][1][j] + acc[rg][2][j])
                                       : (acc[rg][0][j] + acc[rg][1][j]);
                ks += __shfl_xor(ks, 1); ks += __shfl_xor(ks, 2);
                ks += __shfl_xor(ks, 4); ks += __shfl_xor(ks, 8);
                if (lr == 0) kred[wave - 1][rg * 16 + lrow + j] = ks;
            }
        }
    }

    float sq = 0.f, qq = 0.f, sk = 0.f, qk = 0.f, sv = 0.f, qv = 0.f;
    #pragma unroll
    for (int c = 0; c < 3; ++c) {
        const int nb = wave * 3 + c;
        float s = 0.f, q = 0.f;
        #pragma unroll
        for (int rg = 0; rg < 4; ++rg)
            #pragma unroll
            for (int j = 0; j < 4; ++j) { float v = acc[rg][c][j]; s += v; q += v * v; }
        if (nb < 4)      { sq += s; qq += q; }
        else if (nb < 8) { sk += s; qk += q; }
        else             { sv += s; qv += q; }
    }
    #pragma unroll
    for (int off = 1; off < 64; off <<= 1) {
        sq += __shfl_xor(sq, off); qq += __shfl_xor(qq, off);
        sk += __shfl_xor(sk, off); qk += __shfl_xor(qk, off);
        sv += __shfl_xor(sv, off); qv += __shfl_xor(qv, off);
    }
    if (lane == 0) {
        red[wave][0] = sq; red[wave][1] = qq;
        red[wave][2] = sk; red[wave][3] = qk;
        red[wave][4] = sv; red[wave][5] = qv;
    }
    __syncthreads();
    if (tid < 64) ksum[m0 + tid] = kred[0][tid] + kred[1][tid];
    if (tid < 6)
        part[blockIdx.x * 6 + tid] = red[0][tid] + red[1][tid] + red[2][tid] + red[3][tid];
}

// ---------------- kernel 2: flash attention + inlined per-batch stats ---------------
__global__ __launch_bounds__(256) void attn_kernel(const _Float16* __restrict__ q16,
                                                   const _Float16* __restrict__ k16,
                                                   const _Float16* __restrict__ v16t,
                                                   const float* __restrict__ part,
                                                   const float* __restrict__ ksum,
                                                   float* __restrict__ out) {
    __shared__ _Float16 ksm[64][72];
    __shared__ _Float16 vsm[64][72];     // [d][kv]
    __shared__ _Float16 psm[4][16][72];  // per-wave, no barrier needed
    __shared__ float smstats[8];
    const int d_ = blockIdx.x;
    const int b = (d_ & 7) * 4 + ((d_ >> 3) & 3), qt = d_ >> 5;
    const int tid = threadIdx.x, wave = tid >> 6, lane = tid & 63;
    const int lr = lane & 15, lk = (lane >> 4) * 8, lrow = (lane >> 4) * 4;

    // per-batch LN stats from proj partials (replaces stats_reduce kernel)
    if (tid < 6) {
        double s = 0.0;
        for (int i = 0; i < 16; ++i) s += (double)part[(b * 16 + i) * 6 + tid];
        smstats[tid] = (float)s;
    }
    __syncthreads();
    if (tid < 3) {
        double mean = (double)smstats[tid * 2] / 65536.0;
        double var  = (double)smstats[tid * 2 + 1] / 65536.0 - mean * mean;
        smstats[tid * 2]     = (float)mean;
        smstats[tid * 2 + 1] = (float)(1.0 / sqrt(var + 1e-5));
    }
    __syncthreads();
    const float sscale = smstats[1] * smstats[3] * 0.125f * LOG2E;
    const float adjscale = sscale * smstats[0];   // * mq
    const float mv = smstats[4], rv = smstats[5];

    const int q0 = qt * 64 + wave * 16;
    const _Float16* Qb = q16 + ((size_t)b * SEQ + q0) * HD;
    const float* ksb = ksum + b * SEQ;

    f16x8 aq0 = *(const f16x8*)&Qb[(size_t)lr * HD + lk];
    f16x8 aq1 = *(const f16x8*)&Qb[(size_t)lr * HD + 32 + lk];

    f32x4 o[4] = {};
    float mrow[4], lsum[4];
    #pragma unroll
    for (int j = 0; j < 4; ++j) { mrow[j] = -1e30f; lsum[j] = 0.f; }

    for (int kv0 = 0; kv0 < SEQ; kv0 += 64) {
        for (int i = 0; i < 2; ++i) {
            int lin = tid + i * 256;
            int r = lin >> 3, c = (lin & 7) * 8;
            *(f16x8*)&ksm[r][c] = *(const f16x8*)&k16[((size_t)b * SEQ + kv0 + r) * HD + c];
        }
        for (int i = 0; i < 2; ++i) {
            int lin = tid + i * 256;
            int dd = lin >> 3, c = (lin & 7) * 8;
            *(f16x8*)&vsm[dd][c] = *(const f16x8*)&v16t[((size_t)b * HD + dd) * SEQ + kv0 + c];
        }
        __syncthreads();

        f32x4 sa[4];
        float adjv[4];
        __builtin_amdgcn_s_setprio(1);     // T5: favor MFMA wave on CU scheduler
        #pragma unroll
        for (int cb = 0; cb < 4; ++cb) {
            sa[cb] = (f32x4){0.f, 0.f, 0.f, 0.f};
            f16x8 bk0 = *(const f16x8*)&ksm[cb * 16 + lr][lk];
            f16x8 bk1 = *(const f16x8*)&ksm[cb * 16 + lr][32 + lk];
            sa[cb] = __builtin_amdgcn_mfma_f32_16x16x32_f16(aq0, bk0, sa[cb], 0, 0, 0);
            sa[cb] = __builtin_amdgcn_mfma_f32_16x16x32_f16(aq1, bk1, sa[cb], 0, 0, 0);
            adjv[cb] = adjscale * ksb[kv0 + cb * 16 + lr];
        }
        __builtin_amdgcn_s_setprio(0);

        #pragma unroll
        for (int j = 0; j < 4; ++j) {
            float sv0 = sa[0][j] * sscale - adjv[0];
            float sv1 = sa[1][j] * sscale - adjv[1];
            float sv2 = sa[2][j] * sscale - adjv[2];
            float sv3 = sa[3][j] * sscale - adjv[3];
            float pm = fmaxf(fmaxf(sv0, sv1), fmaxf(sv2, sv3));
            pm = fmaxf(pm, __shfl_xor(pm, 1));
            pm = fmaxf(pm, __shfl_xor(pm, 2));
            pm = fmaxf(pm, __shfl_xor(pm, 4));
            pm = fmaxf(pm, __shfl_xor(pm, 8));
            float mnew  = fmaxf(mrow[j], pm);
            float alpha = exp2f(mrow[j] - mnew);
            mrow[j] = mnew;
            float p0 = exp2f(sv0 - mnew), p1 = exp2f(sv1 - mnew);
            float p2 = exp2f(sv2 - mnew), p3 = exp2f(sv3 - mnew);
            sa[0][j] = p0; sa[1][j] = p1; sa[2][j] = p2; sa[3][j] = p3;
            float rs = (p0 + p1) + (p2 + p3);
            rs += __shfl_xor(rs, 1); rs += __shfl_xor(rs, 2);
            rs += __shfl_xor(rs, 4); rs += __shfl_xor(rs, 8);
            lsum[j] = lsum[j] * alpha + rs;
            o[0][j] *= alpha; o[1][j] *= alpha; o[2][j] *= alpha; o[3][j] *= alpha;
        }
        #pragma unroll
        for (int cb = 0; cb < 4; ++cb)
            #pragma unroll
            for (int j = 0; j < 4; ++j)
                psm[wave][lrow + j][cb * 16 + lr] = (_Float16)sa[cb][j];

        f16x8 pa0 = *(const f16x8*)&psm[wave][lr][lk];
        f16x8 pa1 = *(const f16x8*)&psm[wave][lr][32 + lk];
        __builtin_amdgcn_s_setprio(1);
        #pragma unroll
        for (int db = 0; db < 4; ++db) {
            f16x8 bv0 = *(const f16x8*)&vsm[db * 16 + lr][lk];
            f16x8 bv1 = *(const f16x8*)&vsm[db * 16 + lr][32 + lk];
            o[db] = __builtin_amdgcn_mfma_f32_16x16x32_f16(pa0, bv0, o[db], 0, 0, 0);
            o[db] = __builtin_amdgcn_mfma_f32_16x16x32_f16(pa1, bv1, o[db], 0, 0, 0);
        }
        __builtin_amdgcn_s_setprio(0);
        __syncthreads();
    }

    #pragma unroll
    for (int j = 0; j < 4; ++j) {
        float inv = 1.f / lsum[j];
        size_t row = (size_t)b * SEQ + q0 + lrow + j;
        #pragma unroll
        for (int db = 0; db < 4; ++db)
            out[row * HD + db * 16 + lr] = rv * (o[db][j] * inv - mv);
    }
}

extern "C" void kernel_launch(void* const* d_in, const int* in_sizes, int n_in,
                              void* d_out, int out_size, void* d_ws, size_t ws_size,
                              hipStream_t stream) {
    const float* x  = (const float*)d_in[0];
    const float* Wq = (const float*)d_in[1];
    const float* Wk = (const float*)d_in[2];
    const float* Wv = (const float*)d_in[3];
    float* out = (float*)d_out;
    char* ws = (char*)d_ws;

    _Float16* Wt   = (_Float16*)ws;                 // 294912 B
    float* ksum    = (float*)(ws + 0x51000);        // 128 KB
    float* part    = (float*)(ws + 0x72000);        // 12 KB
    _Float16* q16  = (_Float16*)(ws + 0x100000);    // 4 MiB each
    _Float16* k16  = (_Float16*)(ws + 0x500000);
    _Float16* v16t = (_Float16*)(ws + 0x900000);

    pack_w<<<192, 256, 0, stream>>>(Wq, Wk, Wv, Wt);
    proj_kernel<<<MTOT / 64, 256, 0, stream>>>(x, Wt, q16, k16, v16t, part, ksum);
    attn_kernel<<<NB * 16, 256, 0, stream>>>(q16, k16, v16t, part, ksum, out);
}